// Round 1
// baseline (943.823 us; speedup 1.0000x reference)
//
#include <hip/hip_runtime.h>
#include <hip/hip_fp16.h>

// GCN 2-layer, N=100000, F=64, H=128, O=100, out [N,1] fp32.
// out = agg(relu(agg(x)@W1 + b1) . (W2@Wl)) + (b2@Wl + bl)
// Pipeline: partA multi-splits edges into padded dst-buckets; partB computes
// degrees/dinv, 13-bin sorts each bucket by SRC-TILE (8192 srcs = 1MB of y per
// tile), emits fp16 pre-scaled y. fused1: one block per bucket, all-resident
// grid walks tiles in lock-step (per-XCD L2 holds the live tile), accumulating
// gathered y rows into a 64KB LDS f32 tile via ds_add_f32, then MFMA + epilogue.
// out: per-bucket LDS scatter of zz (L2-resident).

#define N_NODES 100000
#define F_IN 64
#define HID 128
#define OUT2 100
#define BSHIFT 8
#define BNODES 256
#define NBUCKETS ((N_NODES + BNODES - 1) / BNODES)  // 391
#define SCAP 4608   // bucket capacity: mean 4096 + 8 sigma (sigma=64)
#define ACHUNK 4096 // edges per partA block
#define NB_PAD 512
#define SENTB 0xFFFFu
#define TSHIFT 13   // src tile = src >> 13 (8192 srcs = 1 MB of y per tile)
#define NTILES 13   // ceil(100000 / 8192)

typedef _Float16 half8 __attribute__((ext_vector_type(8)));
typedef float f32x4 __attribute__((ext_vector_type(4)));

static __device__ __forceinline__ half8 as_half8(uint4 u) {
    union { uint4 u; half8 h; } x; x.u = u; return x.h;
}

// Blocks 0..7: pack W1 (MFMA B-layout, fp16 hi+lo).
// Block 8: v = W2@Wl, c = b2.Wl + bl, init bcur[b] = b*SCAP.
__global__ __launch_bounds__(256) void prep_kernel(
    const float* __restrict__ W1, const float* __restrict__ W2,
    const float* __restrict__ b2, const float* __restrict__ Wl,
    const float* __restrict__ bl,
    float* __restrict__ v, float* __restrict__ c, uint4* __restrict__ Wpk,
    int* __restrict__ bcur) {
    int t = threadIdx.x;
    if (blockIdx.x < 8) {
        // idx: bit10 = part (0=hi,1=lo), bits9..7 = cb, bit6 = kf, bits5..0 = lane
        int idx = blockIdx.x * 256 + t;
        int lane2 = idx & 63;
        int kf    = (idx >> 6) & 1;
        int cb    = (idx >> 7) & 7;
        int part  = (idx >> 10) & 1;
        union { uint4 u; unsigned short s[8]; } pk;
        #pragma unroll
        for (int j = 0; j < 8; ++j) {
            int k    = kf * 32 + (lane2 >> 4) * 8 + j;
            int colg = cb * 16 + (lane2 & 15);
            float w = W1[k * HID + colg];
            __half h = __float2half_rn(w);
            if (part) h = __float2half_rn(w - __half2float(h));
            pk.s[j] = __half_as_ushort(h);
        }
        Wpk[idx] = pk.u;
    } else {
        bcur[t] = t * SCAP;
        bcur[t + 256] = (t + 256) * SCAP;
        if (t < HID) {
            float acc = 0.f;
            for (int k = 0; k < OUT2; ++k) acc += W2[t * OUT2 + k] * Wl[k];
            v[t] = acc;
        } else if (t == HID) {
            float acc = bl[0];
            for (int k = 0; k < OUT2; ++k) acc += b2[k] * Wl[k];
            *c = acc;
        }
    }
}

// Pass A: LDS multi-split into padded dst-buckets; ONE reserve-atomic per
// bucket per block. Packed entry = (src<<8) | (dst&255).
__global__ __launch_bounds__(256) void partA_kernel(
    const int* __restrict__ src, const int* __restrict__ dst,
    int* __restrict__ bcur, unsigned int* __restrict__ ebuf, int E) {
    __shared__ unsigned int stage[ACHUNK];       // 16 KB
    __shared__ unsigned short sb[ACHUNK];        // 8 KB
    __shared__ int hist[NB_PAD];
    __shared__ int ocnt[NB_PAD];
    __shared__ int gbase[NB_PAD];
    __shared__ int cnt2[NB_PAD];
    int t = threadIdx.x;
    int base = blockIdx.x * ACHUNK;
    int total = E - base; if (total > ACHUNK) total = ACHUNK;

    hist[t] = 0; hist[t + 256] = 0;
    cnt2[t] = 0; cnt2[t + 256] = 0;
    __syncthreads();

    unsigned int pe[16];
    unsigned short bk[16];
    #pragma unroll
    for (int k = 0; k < 16; ++k) {
        int e = base + k * 256 + t;
        if (e < E) {
            int s = src[e], d = dst[e];
            pe[k] = ((unsigned int)s << 8) | (unsigned int)(d & (BNODES - 1));
            bk[k] = (unsigned short)(d >> BSHIFT);
            atomicAdd(&hist[bk[k]], 1);
        } else {
            bk[k] = SENTB;
        }
    }
    __syncthreads();
    ocnt[t] = hist[t]; ocnt[t + 256] = hist[t + 256];
    __syncthreads();
    for (int off = 1; off < NB_PAD; off <<= 1) {
        int v0 = (t >= off) ? hist[t - off] : 0;
        int v1 = hist[t + 256 - off];
        __syncthreads();
        hist[t] += v0; hist[t + 256] += v1;
        __syncthreads();
    }
    #pragma unroll
    for (int i = 0; i < 2; ++i) {
        int b = (t + i * 256 + blockIdx.x * 131) & (NB_PAD - 1);
        int cc = ocnt[b];
        if (cc > 0 && b < NBUCKETS) gbase[b] = atomicAdd(&bcur[b], cc);
    }
    __syncthreads();
    #pragma unroll
    for (int k = 0; k < 16; ++k) {
        if (bk[k] != SENTB) {
            int b = bk[k];
            int pos = (hist[b] - ocnt[b]) + atomicAdd(&cnt2[b], 1);
            stage[pos] = pe[k];
            sb[pos] = (unsigned short)b;
        }
    }
    __syncthreads();
    #pragma unroll
    for (int k = 0; k < 16; ++k) {
        int idx = k * 256 + t;
        if (idx < total) {
            int b = sb[idx];
            int lo = hist[b] - ocnt[b];
            ebuf[gbase[b] + (idx - lo)] = stage[idx];
        }
    }
}

// Pass B: per bucket: dl-histogram -> dinv; 13-bin counting sort by src-tile
// (keeps FULL entries (src<<8|dl)); emits fp16 pre-scaled y rows.
__global__ __launch_bounds__(256) void partB_kernel(
    const int* __restrict__ bcur, unsigned int* __restrict__ csr,
    float* __restrict__ dinv,
    const float4* __restrict__ x4, __half2* __restrict__ y2, int n) {
    __shared__ int lcnt[BNODES];
    __shared__ float sdinv[BNODES];
    __shared__ int tcnt[16];
    __shared__ int tstart[16];
    __shared__ int tcur[16];
    __shared__ unsigned int sbuf[SCAP];
    int b = blockIdx.x, t = threadIdx.x;
    int node0 = b << BSHIFT;
    int nlocal = min(BNODES, n - node0);
    int base = b * SCAP;
    int cnt = bcur[b] - base;
    lcnt[t] = 0;
    if (t < 16) tcnt[t] = 0;
    __syncthreads();
    unsigned int er[SCAP / 256];
    #pragma unroll
    for (int k = 0; k < SCAP / 256; ++k) {
        int idx = k * 256 + t;
        er[k] = (idx < cnt) ? csr[base + idx] : 0xFFFFFFFFu;
        if (er[k] != 0xFFFFFFFFu) {
            atomicAdd(&lcnt[er[k] & (BNODES - 1)], 1);
            atomicAdd(&tcnt[er[k] >> (8 + TSHIFT)], 1);
        }
    }
    __syncthreads();
    int own = lcnt[t];
    sdinv[t] = rsqrtf((float)own + 1.0f);
    if (t < nlocal) dinv[node0 + t] = sdinv[t];
    if (t == 0) {
        int s = 0;
        #pragma unroll
        for (int i = 0; i < NTILES; ++i) { tstart[i] = s; s += tcnt[i]; }
    }
    __syncthreads();
    if (t < NTILES) tcur[t] = tstart[t];
    __syncthreads();
    #pragma unroll
    for (int k = 0; k < SCAP / 256; ++k) {
        unsigned int e = er[k];
        if (e != 0xFFFFFFFFu) {
            int p = atomicAdd(&tcur[e >> (8 + TSHIFT)], 1);
            sbuf[p] = e;
        }
    }
    __syncthreads();
    for (int idx = t; idx < cnt; idx += 256) csr[base + idx] = sbuf[idx];
    // y emission (dinv[src]-prescaled fp16 rows)
    for (int i = t; i < nlocal * 16; i += 256) {
        int nl = i >> 4;
        int gi = (node0 + nl) * 16 + (i & 15);
        float di = sdinv[nl];
        float4 xv = x4[gi];
        y2[2 * gi]     = __floats2half2_rn(xv.x * di, xv.y * di);
        y2[2 * gi + 1] = __floats2half2_rn(xv.z * di, xv.w * di);
    }
}

// Fused layer 1: block = bucket (256 dst nodes). Edges are tile-sorted; the
// all-resident grid walks tiles in lock-step so the live y-tile stays L2-hot.
// lane = feature (64 lanes x 2B = one coalesced 128B row per edge);
// accumulate into LDS f32 via ds_add_f32 (2 lanes/bank = conflict-free).
__global__ __launch_bounds__(256) void fused1_kernel(
    const unsigned short* __restrict__ yh, const unsigned int* __restrict__ csr,
    const int* __restrict__ bcur,
    const float* __restrict__ dinv, const uint4* __restrict__ Wpk,
    const float* __restrict__ b1, const float* __restrict__ v,
    float* __restrict__ zz, int n) {
    __shared__ float accf[BNODES * 64];   // 64 KB -> 2 blocks/CU, 391 blocks all resident
    int t = threadIdx.x;
    int lane = t & 63, wave = t >> 6;
    int b = blockIdx.x;
    int node0 = b << BSHIFT;
    int nlocal = min(BNODES, n - node0);
    int base = b * SCAP;
    int end = bcur[b];

    // self-loop init: acc[r][j] = y[node0+r][j] (already dinv[src]-scaled)
    for (int r = wave; r < BNODES; r += 4) {
        float vv = 0.f;
        if (r < nlocal) vv = __half2float(__ushort_as_half(yh[(node0 + r) * 64 + lane]));
        accf[r * 64 + lane] = vv;
    }
    __syncthreads();

    // edge accumulation: 64-edge chunks, waves interleaved (stay tile-synced),
    // 16 gathers in flight before consuming.
    for (int bb = base + wave * 64; bb < end; bb += 256) {
        int rem = end - bb;
        int lim = rem < 64 ? rem : 64;
        unsigned int ee = (lane < lim) ? csr[bb + lane] : 0u;
        for (int kk = 0; kk < lim; kk += 16) {
            int kn0 = min(8, lim - kk);
            int kn1 = min(8, lim - kk - 8);
            unsigned short u0[8], u1[8];
            int d0[8], d1[8];
            #pragma unroll
            for (int j = 0; j < 8; ++j) if (j < kn0) {
                unsigned int e = __shfl(ee, kk + j, 64);
                d0[j] = (int)(e & 255u);
                u0[j] = yh[(e >> 8) * 64 + lane];
            }
            #pragma unroll
            for (int j = 0; j < 8; ++j) if (j < kn1) {
                unsigned int e = __shfl(ee, kk + 8 + j, 64);
                d1[j] = (int)(e & 255u);
                u1[j] = yh[(e >> 8) * 64 + lane];
            }
            #pragma unroll
            for (int j = 0; j < 8; ++j) if (j < kn0)
                atomicAdd(&accf[d0[j] * 64 + lane],
                          __half2float(__ushort_as_half(u0[j])));
            #pragma unroll
            for (int j = 0; j < 8; ++j) if (j < kn1)
                atomicAdd(&accf[d1[j] * 64 + lane],
                          __half2float(__ushort_as_half(u1[j])));
        }
    }
    __syncthreads();

    // MFMA + epilogue: each wave handles 4 sub-tiles of 16 nodes.
    int mm = lane & 15, kq = lane >> 4;
    for (int i = 0; i < 4; ++i) {
        int st = wave * 4 + i;
        int row = st * 16 + mm;
        float di = (row < nlocal) ? dinv[node0 + row] : 0.f;
        const float* ap = &accf[row * 64 + kq * 8];
        half8 A0, A1;
        #pragma unroll
        for (int j = 0; j < 8; ++j) {
            A0[j] = (_Float16)(di * ap[j]);
            A1[j] = (_Float16)(di * ap[32 + j]);
        }
        f32x4 acc[8];
        #pragma unroll
        for (int cb = 0; cb < 8; ++cb) acc[cb] = (f32x4){0.f, 0.f, 0.f, 0.f};
        #pragma unroll
        for (int cb = 0; cb < 8; ++cb) {
            half8 bh0 = as_half8(Wpk[(cb * 2 + 0) * 64 + lane]);
            half8 bh1 = as_half8(Wpk[(cb * 2 + 1) * 64 + lane]);
            half8 bl0 = as_half8(Wpk[1024 + (cb * 2 + 0) * 64 + lane]);
            half8 bl1 = as_half8(Wpk[1024 + (cb * 2 + 1) * 64 + lane]);
            acc[cb] = __builtin_amdgcn_mfma_f32_16x16x32_f16(A0, bh0, acc[cb], 0, 0, 0);
            acc[cb] = __builtin_amdgcn_mfma_f32_16x16x32_f16(A1, bh1, acc[cb], 0, 0, 0);
            acc[cb] = __builtin_amdgcn_mfma_f32_16x16x32_f16(A0, bl0, acc[cb], 0, 0, 0);
            acc[cb] = __builtin_amdgcn_mfma_f32_16x16x32_f16(A1, bl1, acc[cb], 0, 0, 0);
        }
        float zp[4] = {0.f, 0.f, 0.f, 0.f};
        #pragma unroll
        for (int cb = 0; cb < 8; ++cb) {
            int colg = cb * 16 + mm;
            float bb1 = b1[colg], vv = v[colg];
            #pragma unroll
            for (int r = 0; r < 4; ++r) {
                float h = acc[cb][r] + bb1;
                h = fmaxf(h, 0.f);
                zp[r] += h * vv;
            }
        }
        #pragma unroll
        for (int off = 1; off < 16; off <<= 1) {
            #pragma unroll
            for (int r = 0; r < 4; ++r) zp[r] += __shfl_xor(zp[r], off, 64);
        }
        if (mm == 0) {
            int nb = st * 16 + kq * 4;
            #pragma unroll
            for (int r = 0; r < 4; ++r)
                if (nb + r < nlocal)
                    zz[node0 + nb + r] = dinv[node0 + nb + r] * zp[r];
        }
    }
}

// Layer 2 (collapsed): per-bucket LDS scatter of zz (zz = 400KB, L2-resident).
// out[i] = c + dinv[i]*(zz[i] + sum_in zz[s]).
__global__ __launch_bounds__(256) void out_kernel(
    const int* __restrict__ bcur, const unsigned int* __restrict__ csr,
    const float* __restrict__ dinv, const float* __restrict__ zz,
    const float* __restrict__ c, float* __restrict__ out, int n) {
    __shared__ float acc2[BNODES];
    int b = blockIdx.x, t = threadIdx.x;
    int node0 = b << BSHIFT;
    int nlocal = min(BNODES, n - node0);
    int base = b * SCAP;
    int cnt = bcur[b] - base;
    acc2[t] = 0.f;
    __syncthreads();
    unsigned int er[SCAP / 256];
    #pragma unroll
    for (int k = 0; k < SCAP / 256; ++k) {
        int idx = k * 256 + t;
        er[k] = (idx < cnt) ? csr[base + idx] : 0xFFFFFFFFu;
    }
    #pragma unroll
    for (int k = 0; k < SCAP / 256; ++k) {
        if (er[k] != 0xFFFFFFFFu) {
            float z = zz[er[k] >> 8];
            atomicAdd(&acc2[er[k] & (BNODES - 1)], z);
        }
    }
    __syncthreads();
    if (t < nlocal) {
        int node = node0 + t;
        out[node] = c[0] + dinv[node] * (acc2[t] + zz[node]);
    }
}

extern "C" void kernel_launch(void* const* d_in, const int* in_sizes, int n_in,
                              void* d_out, int out_size, void* d_ws, size_t ws_size,
                              hipStream_t stream) {
    const float* x  = (const float*)d_in[0];
    const int*   ei = (const int*)d_in[1];
    const float* W1 = (const float*)d_in[2];
    const float* b1 = (const float*)d_in[3];
    const float* W2 = (const float*)d_in[4];
    const float* b2 = (const float*)d_in[5];
    const float* Wl = (const float*)d_in[6];
    const float* bl = (const float*)d_in[7];
    float* out = (float*)d_out;

    int E = in_sizes[1] / 2;
    const int* src = ei;
    const int* dst = ei + E;

    float* ws      = (float*)d_ws;
    float* dinv    = ws;                        // N
    float* zz      = dinv + N_NODES;            // N
    float* v       = zz + N_NODES;              // 128
    float* c       = v + HID;                   // 4
    int*   bcur    = (int*)(c + 4);             // 512
    int*   csr     = bcur + 512;                // NBUCKETS*SCAP
    uint4* Wpk     = (uint4*)(csr + (size_t)NBUCKETS * SCAP);  // 2048 uint4
    __half* y      = (__half*)((float*)Wpk + 8192);            // N*64 halves

    int nchunks = (E + ACHUNK - 1) / ACHUNK;   // 391

    prep_kernel<<<9, 256, 0, stream>>>(W1, W2, b2, Wl, bl, v, c, Wpk, bcur);
    partA_kernel<<<nchunks, 256, 0, stream>>>(src, dst, bcur, (unsigned int*)csr, E);
    partB_kernel<<<NBUCKETS, 256, 0, stream>>>(
        bcur, (unsigned int*)csr, dinv, (const float4*)x, (__half2*)y, N_NODES);
    fused1_kernel<<<NBUCKETS, 256, 0, stream>>>(
        (const unsigned short*)y, (const unsigned int*)csr, bcur,
        dinv, Wpk, b1, v, zz, N_NODES);
    out_kernel<<<NBUCKETS, 256, 0, stream>>>(
        bcur, (const unsigned int*)csr, dinv, zz, c, out, N_NODES);
}

// Round 2
// 880.063 us; speedup vs baseline: 1.0725x; 1.0725x over previous
//
#include <hip/hip_runtime.h>
#include <hip/hip_fp16.h>

// GCN 2-layer, N=100000, F=64, H=128, O=100, out [N,1] fp32.
// out = agg(relu(agg(x)@W1 + b1) . (W2@Wl)) + (b2@Wl + bl)
// Pipeline: partA multi-splits edges into padded dst-buckets; partB computes
// degrees/dinv, 13-bin sorts each bucket by SRC-TILE (8192 srcs = 1MB of y per
// tile), emits fp16 pre-scaled y. fused1: one block per bucket, all-resident
// grid walks tiles in lock-step (per-XCD L2 holds the live tile); gathers use
// the 8-edge x 8-uint4-col wave shape (8 lines per VMEM instr, 8 instrs deep =
// 64 lines in flight per wave); accumulate into LDS f32 at STRIDE 72 (9-float
// sub-blocks) so the scatter is ~2-way bank-conflict-free; then MFMA + epilogue.
// out: per-bucket LDS scatter of zz (L2-resident).

#define N_NODES 100000
#define F_IN 64
#define HID 128
#define OUT2 100
#define BSHIFT 8
#define BNODES 256
#define NBUCKETS ((N_NODES + BNODES - 1) / BNODES)  // 391
#define SCAP 4608   // bucket capacity: mean 4096 + 8 sigma (sigma=64)
#define ACHUNK 4096 // edges per partA block
#define NB_PAD 512
#define SENTB 0xFFFFu
#define TSHIFT 13   // src tile = src >> 13 (8192 srcs = 1 MB of y per tile)
#define NTILES 13   // ceil(100000 / 8192)
#define RSTRIDE 72  // accf floats per node row: 8 blocks x 9 (8 data + 1 pad)

typedef _Float16 half8 __attribute__((ext_vector_type(8)));
typedef float f32x4 __attribute__((ext_vector_type(4)));

static __device__ __forceinline__ half8 as_half8(uint4 u) {
    union { uint4 u; half8 h; } x; x.u = u; return x.h;
}

// Blocks 0..7: pack W1 (MFMA B-layout, fp16 hi+lo).
// Block 8: v = W2@Wl, c = b2.Wl + bl, init bcur[b] = b*SCAP.
__global__ __launch_bounds__(256) void prep_kernel(
    const float* __restrict__ W1, const float* __restrict__ W2,
    const float* __restrict__ b2, const float* __restrict__ Wl,
    const float* __restrict__ bl,
    float* __restrict__ v, float* __restrict__ c, uint4* __restrict__ Wpk,
    int* __restrict__ bcur) {
    int t = threadIdx.x;
    if (blockIdx.x < 8) {
        // idx: bit10 = part (0=hi,1=lo), bits9..7 = cb, bit6 = kf, bits5..0 = lane
        int idx = blockIdx.x * 256 + t;
        int lane2 = idx & 63;
        int kf    = (idx >> 6) & 1;
        int cb    = (idx >> 7) & 7;
        int part  = (idx >> 10) & 1;
        union { uint4 u; unsigned short s[8]; } pk;
        #pragma unroll
        for (int j = 0; j < 8; ++j) {
            int k    = kf * 32 + (lane2 >> 4) * 8 + j;
            int colg = cb * 16 + (lane2 & 15);
            float w = W1[k * HID + colg];
            __half h = __float2half_rn(w);
            if (part) h = __float2half_rn(w - __half2float(h));
            pk.s[j] = __half_as_ushort(h);
        }
        Wpk[idx] = pk.u;
    } else {
        bcur[t] = t * SCAP;
        bcur[t + 256] = (t + 256) * SCAP;
        if (t < HID) {
            float acc = 0.f;
            for (int k = 0; k < OUT2; ++k) acc += W2[t * OUT2 + k] * Wl[k];
            v[t] = acc;
        } else if (t == HID) {
            float acc = bl[0];
            for (int k = 0; k < OUT2; ++k) acc += b2[k] * Wl[k];
            *c = acc;
        }
    }
}

// Pass A: LDS multi-split into padded dst-buckets; ONE reserve-atomic per
// bucket per block. Packed entry = (src<<8) | (dst&255).
__global__ __launch_bounds__(256) void partA_kernel(
    const int* __restrict__ src, const int* __restrict__ dst,
    int* __restrict__ bcur, unsigned int* __restrict__ ebuf, int E) {
    __shared__ unsigned int stage[ACHUNK];       // 16 KB
    __shared__ unsigned short sb[ACHUNK];        // 8 KB
    __shared__ int hist[NB_PAD];
    __shared__ int ocnt[NB_PAD];
    __shared__ int gbase[NB_PAD];
    __shared__ int cnt2[NB_PAD];
    int t = threadIdx.x;
    int base = blockIdx.x * ACHUNK;
    int total = E - base; if (total > ACHUNK) total = ACHUNK;

    hist[t] = 0; hist[t + 256] = 0;
    cnt2[t] = 0; cnt2[t + 256] = 0;
    __syncthreads();

    unsigned int pe[16];
    unsigned short bk[16];
    #pragma unroll
    for (int k = 0; k < 16; ++k) {
        int e = base + k * 256 + t;
        if (e < E) {
            int s = src[e], d = dst[e];
            pe[k] = ((unsigned int)s << 8) | (unsigned int)(d & (BNODES - 1));
            bk[k] = (unsigned short)(d >> BSHIFT);
            atomicAdd(&hist[bk[k]], 1);
        } else {
            bk[k] = SENTB;
        }
    }
    __syncthreads();
    ocnt[t] = hist[t]; ocnt[t + 256] = hist[t + 256];
    __syncthreads();
    for (int off = 1; off < NB_PAD; off <<= 1) {
        int v0 = (t >= off) ? hist[t - off] : 0;
        int v1 = hist[t + 256 - off];
        __syncthreads();
        hist[t] += v0; hist[t + 256] += v1;
        __syncthreads();
    }
    #pragma unroll
    for (int i = 0; i < 2; ++i) {
        int b = (t + i * 256 + blockIdx.x * 131) & (NB_PAD - 1);
        int cc = ocnt[b];
        if (cc > 0 && b < NBUCKETS) gbase[b] = atomicAdd(&bcur[b], cc);
    }
    __syncthreads();
    #pragma unroll
    for (int k = 0; k < 16; ++k) {
        if (bk[k] != SENTB) {
            int b = bk[k];
            int pos = (hist[b] - ocnt[b]) + atomicAdd(&cnt2[b], 1);
            stage[pos] = pe[k];
            sb[pos] = (unsigned short)b;
        }
    }
    __syncthreads();
    #pragma unroll
    for (int k = 0; k < 16; ++k) {
        int idx = k * 256 + t;
        if (idx < total) {
            int b = sb[idx];
            int lo = hist[b] - ocnt[b];
            ebuf[gbase[b] + (idx - lo)] = stage[idx];
        }
    }
}

// Pass B: per bucket: dl-histogram -> dinv; 13-bin counting sort by src-tile
// (keeps FULL entries (src<<8|dl)); emits fp16 pre-scaled y rows.
__global__ __launch_bounds__(256) void partB_kernel(
    const int* __restrict__ bcur, unsigned int* __restrict__ csr,
    float* __restrict__ dinv,
    const float4* __restrict__ x4, __half2* __restrict__ y2, int n) {
    __shared__ int lcnt[BNODES];
    __shared__ float sdinv[BNODES];
    __shared__ int tcnt[16];
    __shared__ int tstart[16];
    __shared__ int tcur[16];
    __shared__ unsigned int sbuf[SCAP];
    int b = blockIdx.x, t = threadIdx.x;
    int node0 = b << BSHIFT;
    int nlocal = min(BNODES, n - node0);
    int base = b * SCAP;
    int cnt = bcur[b] - base;
    lcnt[t] = 0;
    if (t < 16) tcnt[t] = 0;
    __syncthreads();
    unsigned int er[SCAP / 256];
    #pragma unroll
    for (int k = 0; k < SCAP / 256; ++k) {
        int idx = k * 256 + t;
        er[k] = (idx < cnt) ? csr[base + idx] : 0xFFFFFFFFu;
        if (er[k] != 0xFFFFFFFFu) {
            atomicAdd(&lcnt[er[k] & (BNODES - 1)], 1);
            atomicAdd(&tcnt[er[k] >> (8 + TSHIFT)], 1);
        }
    }
    __syncthreads();
    int own = lcnt[t];
    sdinv[t] = rsqrtf((float)own + 1.0f);
    if (t < nlocal) dinv[node0 + t] = sdinv[t];
    if (t == 0) {
        int s = 0;
        #pragma unroll
        for (int i = 0; i < NTILES; ++i) { tstart[i] = s; s += tcnt[i]; }
    }
    __syncthreads();
    if (t < NTILES) tcur[t] = tstart[t];
    __syncthreads();
    #pragma unroll
    for (int k = 0; k < SCAP / 256; ++k) {
        unsigned int e = er[k];
        if (e != 0xFFFFFFFFu) {
            int p = atomicAdd(&tcur[e >> (8 + TSHIFT)], 1);
            sbuf[p] = e;
        }
    }
    __syncthreads();
    for (int idx = t; idx < cnt; idx += 256) csr[base + idx] = sbuf[idx];
    // y emission (dinv[src]-prescaled fp16 rows)
    for (int i = t; i < nlocal * 16; i += 256) {
        int nl = i >> 4;
        int gi = (node0 + nl) * 16 + (i & 15);
        float di = sdinv[nl];
        float4 xv = x4[gi];
        y2[2 * gi]     = __floats2half2_rn(xv.x * di, xv.y * di);
        y2[2 * gi + 1] = __floats2half2_rn(xv.z * di, xv.w * di);
    }
}

// Fused layer 1: block = bucket (256 dst nodes). Edges are tile-sorted; the
// all-resident grid walks tiles in lock-step so the live y-tile stays L2-hot.
// Gather shape: 64 lanes = 8 edges (q=lane>>3) x 8 uint4 cols (col=lane&7);
// one VMEM instr touches 8 distinct 128B rows, 8 instrs issued back-to-back
// => 64 lines in flight per wave. Scatter into accf at stride 72 (col*9+j):
// bank = (8*dl + 9*col + j) & 31 -> collisions need same col AND dl==dl' mod 4
// => expected ~2-way (free).
__global__ __launch_bounds__(256) void fused1_kernel(
    const uint4* __restrict__ y4, const unsigned short* __restrict__ yh,
    const unsigned int* __restrict__ csr, const int* __restrict__ bcur,
    const float* __restrict__ dinv, const uint4* __restrict__ Wpk,
    const float* __restrict__ b1, const float* __restrict__ v,
    float* __restrict__ zz, int n) {
    __shared__ float accf[BNODES * RSTRIDE];   // 72 KB -> 2 blocks/CU, all resident
    int t = threadIdx.x;
    int lane = t & 63, wave = t >> 6;
    int q = lane >> 3, col = lane & 7;
    int b = blockIdx.x;
    int node0 = b << BSHIFT;
    int nlocal = min(BNODES, n - node0);
    int base = b * SCAP;
    int end = bcur[b];
    int cnt = end - base;

    // self-loop init: acc[r][f] = y[node0+r][f] (already dinv[src]-scaled)
    for (int r = wave; r < BNODES; r += 4) {
        float vv = 0.f;
        if (r < nlocal) vv = __half2float(__ushort_as_half(yh[(node0 + r) * 64 + lane]));
        accf[r * RSTRIDE + (lane >> 3) * 9 + (lane & 7)] = vv;
    }
    __syncthreads();

    // edge accumulation: wave handles 64-edge chunks (stride 256 across waves).
    int nrounds = (cnt + 255) >> 8;
    for (int r = 0; r < nrounds; ++r) {
        int bb = base + r * 256 + wave * 64;
        int eidx = bb + lane;
        unsigned int ee = (eidx < end) ? csr[eidx] : 0xFFFFFFFFu;
        uint4 u[8];
        int dl[8];
        #pragma unroll
        for (int g = 0; g < 8; ++g) {
            unsigned int e = __shfl(ee, g * 8 + q, 64);
            bool valid = (e != 0xFFFFFFFFu);
            int srow = valid ? (int)(e >> 8) : 0;
            dl[g] = (int)(e & 255u);           // 255 for invalid: safe addr
            u[g] = y4[srow * 8 + col];
            if (!valid) u[g] = (uint4){0u, 0u, 0u, 0u};  // add 0.0f = no-op
        }
        #pragma unroll
        for (int g = 0; g < 8; ++g) {
            const __half* hp = (const __half*)&u[g];
            float* rowp = &accf[dl[g] * RSTRIDE + col * 9];
            #pragma unroll
            for (int j = 0; j < 8; ++j)
                atomicAdd(&rowp[j], __half2float(hp[j]));
        }
    }
    __syncthreads();

    // MFMA + epilogue: each wave handles 4 sub-tiles of 16 nodes.
    int mm = lane & 15, kq = lane >> 4;
    for (int i = 0; i < 4; ++i) {
        int st = wave * 4 + i;
        int row = st * 16 + mm;
        float di = (row < nlocal) ? dinv[node0 + row] : 0.f;
        const float* ap = &accf[row * RSTRIDE];
        half8 A0, A1;
        #pragma unroll
        for (int j = 0; j < 8; ++j) {
            A0[j] = (_Float16)(di * ap[kq * 9 + j]);
            A1[j] = (_Float16)(di * ap[(4 + kq) * 9 + j]);
        }
        f32x4 acc[8];
        #pragma unroll
        for (int cb = 0; cb < 8; ++cb) acc[cb] = (f32x4){0.f, 0.f, 0.f, 0.f};
        #pragma unroll
        for (int cb = 0; cb < 8; ++cb) {
            half8 bh0 = as_half8(Wpk[(cb * 2 + 0) * 64 + lane]);
            half8 bh1 = as_half8(Wpk[(cb * 2 + 1) * 64 + lane]);
            half8 bl0 = as_half8(Wpk[1024 + (cb * 2 + 0) * 64 + lane]);
            half8 bl1 = as_half8(Wpk[1024 + (cb * 2 + 1) * 64 + lane]);
            acc[cb] = __builtin_amdgcn_mfma_f32_16x16x32_f16(A0, bh0, acc[cb], 0, 0, 0);
            acc[cb] = __builtin_amdgcn_mfma_f32_16x16x32_f16(A1, bh1, acc[cb], 0, 0, 0);
            acc[cb] = __builtin_amdgcn_mfma_f32_16x16x32_f16(A0, bl0, acc[cb], 0, 0, 0);
            acc[cb] = __builtin_amdgcn_mfma_f32_16x16x32_f16(A1, bl1, acc[cb], 0, 0, 0);
        }
        float zp[4] = {0.f, 0.f, 0.f, 0.f};
        #pragma unroll
        for (int cb = 0; cb < 8; ++cb) {
            int colg = cb * 16 + mm;
            float bb1 = b1[colg], vv = v[colg];
            #pragma unroll
            for (int rr = 0; rr < 4; ++rr) {
                float h = acc[cb][rr] + bb1;
                h = fmaxf(h, 0.f);
                zp[rr] += h * vv;
            }
        }
        #pragma unroll
        for (int off = 1; off < 16; off <<= 1) {
            #pragma unroll
            for (int rr = 0; rr < 4; ++rr) zp[rr] += __shfl_xor(zp[rr], off, 64);
        }
        if (mm == 0) {
            int nb = st * 16 + kq * 4;
            #pragma unroll
            for (int rr = 0; rr < 4; ++rr)
                if (nb + rr < nlocal)
                    zz[node0 + nb + rr] = dinv[node0 + nb + rr] * zp[rr];
        }
    }
}

// Layer 2 (collapsed): per-bucket LDS scatter of zz (zz = 400KB, L2-resident).
// out[i] = c + dinv[i]*(zz[i] + sum_in zz[s]).
__global__ __launch_bounds__(256) void out_kernel(
    const int* __restrict__ bcur, const unsigned int* __restrict__ csr,
    const float* __restrict__ dinv, const float* __restrict__ zz,
    const float* __restrict__ c, float* __restrict__ out, int n) {
    __shared__ float acc2[BNODES];
    int b = blockIdx.x, t = threadIdx.x;
    int node0 = b << BSHIFT;
    int nlocal = min(BNODES, n - node0);
    int base = b * SCAP;
    int cnt = bcur[b] - base;
    acc2[t] = 0.f;
    __syncthreads();
    unsigned int er[SCAP / 256];
    #pragma unroll
    for (int k = 0; k < SCAP / 256; ++k) {
        int idx = k * 256 + t;
        er[k] = (idx < cnt) ? csr[base + idx] : 0xFFFFFFFFu;
    }
    #pragma unroll
    for (int k = 0; k < SCAP / 256; ++k) {
        if (er[k] != 0xFFFFFFFFu) {
            float z = zz[er[k] >> 8];
            atomicAdd(&acc2[er[k] & (BNODES - 1)], z);
        }
    }
    __syncthreads();
    if (t < nlocal) {
        int node = node0 + t;
        out[node] = c[0] + dinv[node] * (acc2[t] + zz[node]);
    }
}

extern "C" void kernel_launch(void* const* d_in, const int* in_sizes, int n_in,
                              void* d_out, int out_size, void* d_ws, size_t ws_size,
                              hipStream_t stream) {
    const float* x  = (const float*)d_in[0];
    const int*   ei = (const int*)d_in[1];
    const float* W1 = (const float*)d_in[2];
    const float* b1 = (const float*)d_in[3];
    const float* W2 = (const float*)d_in[4];
    const float* b2 = (const float*)d_in[5];
    const float* Wl = (const float*)d_in[6];
    const float* bl = (const float*)d_in[7];
    float* out = (float*)d_out;

    int E = in_sizes[1] / 2;
    const int* src = ei;
    const int* dst = ei + E;

    float* ws      = (float*)d_ws;
    float* dinv    = ws;                        // N
    float* zz      = dinv + N_NODES;            // N
    float* v       = zz + N_NODES;              // 128
    float* c       = v + HID;                   // 4
    int*   bcur    = (int*)(c + 4);             // 512
    int*   csr     = bcur + 512;                // NBUCKETS*SCAP
    uint4* Wpk     = (uint4*)(csr + (size_t)NBUCKETS * SCAP);  // 2048 uint4
    __half* y      = (__half*)((float*)Wpk + 8192);            // N*64 halves

    int nchunks = (E + ACHUNK - 1) / ACHUNK;   // 391

    prep_kernel<<<9, 256, 0, stream>>>(W1, W2, b2, Wl, bl, v, c, Wpk, bcur);
    partA_kernel<<<nchunks, 256, 0, stream>>>(src, dst, bcur, (unsigned int*)csr, E);
    partB_kernel<<<NBUCKETS, 256, 0, stream>>>(
        bcur, (unsigned int*)csr, dinv, (const float4*)x, (__half2*)y, N_NODES);
    fused1_kernel<<<NBUCKETS, 256, 0, stream>>>(
        (const uint4*)y, (const unsigned short*)y, (const unsigned int*)csr,
        bcur, dinv, Wpk, b1, v, zz, N_NODES);
    out_kernel<<<NBUCKETS, 256, 0, stream>>>(
        bcur, (const unsigned int*)csr, dinv, zz, c, out, N_NODES);
}